// Round 9
// baseline (279.380 us; speedup 1.0000x reference)
//
#include <hip/hip_runtime.h>
#include <math.h>

// BVP Helmholtz-residual PINN via MFMA, round 15.
// Round-14 (B-reuse x4, 3 blocks/CU): 210 -> 201 us, MfmaUtil 39.7. Model
// check vs all 6 measurements: MFMA pipe work = 198.7K cy/SIMD = 41% of
// wall (== counter); MfmaUtil+trueVALU+LDS ~ 96% -> pipes still additive.
// r8 anomaly decoded: 2 dedicated MFMA-waves/SIMD -> 36% pipe => per-wave
// issue ~18%; then convoyed 4-wave GEMM phases (60% of wall) x 72% = 43%
// overall == r6/r13/r14. Blocks CONVOY (same durations, simultaneous
// dispatch): GEMM phases idle VALU, jet phases idle MFMA.
// Round-15: break the convoy - one-shot s_sleep stagger keyed on
// co-residency slot: key=(b+(b>>8))%3 (distinct under both {i,i+256,i+512}
// and {3i,3i+1,3i+2} packing), delay = key*~9.6K cy ~ one phase. Offsets
// persist (equal block durations; contention pushes toward anti-phase).
// Everything else = round-14 champion verbatim.

typedef __attribute__((ext_vector_type(8))) short short8;
typedef __attribute__((ext_vector_type(4))) float floatx4;
typedef unsigned short ushort_t;
typedef unsigned int uint_t;

#define PBLK 16
#define NS 5   // jet streams: 0=v 1=dx 2=dy 3=dz 4=weighted-Laplacian

#define CXX 0.09f     // (YC*ZC)^2 = (0.5*0.6)^2
#define CYY 0.1764f   // (XC*ZC)^2 = (0.7*0.6)^2
#define CZZ 0.1225f   // (XC*YC)^2 = (0.7*0.5)^2

__device__ __forceinline__ ushort_t f2bf(float f) {
    uint_t u = __float_as_uint(f);
    return (ushort_t)((u + 0x7FFFu + ((u >> 16) & 1u)) >> 16);  // RNE
}
// pack2bf(f0,f1): {bf16(f0), bf16(f1)} in one u32 (f0 low). Round-half-up.
__device__ __forceinline__ uint_t pack2bf(float f0, float f1) {
    uint_t u0 = __float_as_uint(f0) + 0x8000u;
    uint_t u1 = __float_as_uint(f1) + 0x8000u;
    return __builtin_amdgcn_perm(u1, u0, 0x07060302u);
}
__device__ __forceinline__ float fast_tanh(float u) {
    float e = __expf(2.f * u);
    return 1.f - 2.f / (e + 1.f);   // exact at +-inf for finite u
}

// ws: 2 layers x 16 row-tiles x 8 kc x 64 lanes x 16B = 256 KB.
// A-frag lane (m=lane&15, qa=lane>>4) slot j:
//   layer0 (W2, natural):  col = kc*32 + 8*qa + j
//   layer1 (W3, permuted): col = kc*32 + 16*(j>>2) + 4*qa + (j&3)
__global__ void prep_split(const float* __restrict__ W2, const float* __restrict__ W3,
                           short8* __restrict__ ws) {
    int t16 = blockIdx.x * blockDim.x + threadIdx.x;  // 0..16383
    int lane = t16 & 63;
    int kc = (t16 >> 6) & 7;
    int tt = (t16 >> 9) & 15;
    int l = t16 >> 13;
    const float* W = l ? W3 : W2;
    int row = tt * 16 + (lane & 15);
    int qa = lane >> 4;
    const float* src = W + row * 256 + kc * 32 + (l ? 4 * qa : 8 * qa);
    float4 va = *(const float4*)src;
    float4 vb = *(const float4*)(src + (l ? 16 : 4));
    float v[8] = {va.x, va.y, va.z, va.w, vb.x, vb.y, vb.z, vb.w};
    short8 hi8;
    #pragma unroll
    for (int j = 0; j < 8; ++j) hi8[j] = (short)f2bf(v[j]);   // RNE (runs once)
    ws[l * 8192 + tt * 512 + kc * 64 + lane] = hi8;
}

__global__ __launch_bounds__(256, 3)
void bvp_main(const float* __restrict__ gx, const float* __restrict__ gy,
              const float* __restrict__ gz, const float* __restrict__ gf,
              const float* __restrict__ W1, const float* __restrict__ b1,
              const float* __restrict__ b2, const float* __restrict__ b3,
              const float* __restrict__ W4, const float* __restrict__ b4,
              const short8* __restrict__ wsA, float* __restrict__ out, int N) {
    __shared__ short8 Bsh[NS * 8 * 64];  // 40960 B: B[s][kt][lane]
    __shared__ float red[4][16][4];      // 1 KB cross-wave reduction scratch

    // ---- convoy-buster: stagger co-resident blocks by ~1 phase each ----
    {
        const int key = (int)((blockIdx.x + (blockIdx.x >> 8)) % 3u);
        #pragma unroll 1
        for (int i = 0; i < key * 10; ++i) __builtin_amdgcn_s_sleep(15);
    }

    const int tid = threadIdx.x;
    const int w = tid >> 6, lane = tid & 63;   // w in 0..3
    const int n15 = lane & 15, qc = lane >> 4;
    const int pbase = blockIdx.x * PBLK;
    const short8* __restrict__ wsA3 = wsA + 8192;

    floatx4 acc[4][NS];  // 4 row-tiles (64 rows) x 5 streams = 80 VGPR
    short8 a0[4], a1[4];

    // GEMM-2 A(kc=0): issue now, covered by layer-1 math.
    #pragma unroll
    for (int rt = 0; rt < 4; ++rt) a0[rt] = wsA[(4 * w + rt) * 512 + lane];

    // ---------------- layer 1 (VALU) -> B fragments ----------------
    // pp = tid&15: 16-lane groups write contiguous 256B -> conflict-free;
    // 256 threads: each handles two u8 neuron-groups sequentially.
    // u linear in x,y,z -> L_u = 0, so L_h = c*(cxx*wx^2+cyy*wy^2+czz*wz^2).
    {
        const int pp = tid & 15;
        const int pidx = min(pbase + pp, N - 1);
        const float xi = gx[pidx], yi = gy[pidx], zi = gz[pidx], fi = gf[pidx];
        #pragma unroll
        for (int g = 0; g < 2; ++g) {
            const int u8 = (tid >> 4) + 16 * g;   // 0..31: neurons 8*u8..+7
            float hv[NS][8];
            #pragma unroll
            for (int r = 0; r < 8; ++r) {
                const int i = u8 * 8 + r;
                float4 wv = *(const float4*)(W1 + 4 * i);
                float u = fmaf(wv.x, xi, fmaf(wv.y, yi, fmaf(wv.z, zi, fmaf(wv.w, fi, b1[i]))));
                float t = fast_tanh(u), s = 1.f - t * t, c = -2.f * t * s;
                float wq = fmaf(CXX * wv.x, wv.x, fmaf(CYY * wv.y, wv.y, CZZ * wv.z * wv.z));
                hv[0][r] = t;
                hv[1][r] = s * wv.x; hv[2][r] = s * wv.y; hv[3][r] = s * wv.z;
                hv[4][r] = c * wq;
            }
            const int kt = u8 >> 2, qb = u8 & 3;  // k-slot qb*8+r (natural order)
            #pragma unroll
            for (int s = 0; s < NS; ++s) {
                union { short8 s8; uint_t u4[4]; } v;
                #pragma unroll
                for (int j = 0; j < 4; ++j)
                    v.u4[j] = pack2bf(hv[s][2 * j], hv[s][2 * j + 1]);
                Bsh[(s * 8 + kt) * 64 + qb * 16 + pp] = v.s8;
            }
        }
    }
    __syncthreads();

    // K-loop: A 1-deep global prefetch (L2-resident), B single-buffer LDS.
    // One ds_read_b128 feeds 4 MFMAs (rt reuse x4).
    auto run_gemm = [&](const short8* __restrict__ A) {
        #pragma unroll
        for (int rt = 0; rt < 4; ++rt)
            #pragma unroll
            for (int ct = 0; ct < NS; ++ct) acc[rt][ct] = (floatx4){0.f, 0.f, 0.f, 0.f};
        #pragma unroll
        for (int kc = 0; kc < 8; ++kc) {
            if (kc < 7) {
                #pragma unroll
                for (int rt = 0; rt < 4; ++rt)
                    a1[rt] = A[(4 * w + rt) * 512 + (kc + 1) * 64 + lane];
            }
            short8 b[NS];
            #pragma unroll
            for (int ct = 0; ct < NS; ++ct) b[ct] = Bsh[(ct * 8 + kc) * 64 + lane];
            #pragma unroll
            for (int ct = 0; ct < NS; ++ct)
                #pragma unroll
                for (int rt = 0; rt < 4; ++rt)
                    acc[rt][ct] = __builtin_amdgcn_mfma_f32_16x16x32_bf16(a0[rt], b[ct], acc[rt][ct], 0, 0, 0);
            if (kc < 7) {
                #pragma unroll
                for (int rt = 0; rt < 4; ++rt) a0[rt] = a1[rt];
            }
        }
    };

    // ---------------- GEMM 2 ----------------
    run_gemm(wsA);
    __syncthreads();   // all waves done reading layer-2 B

    // GEMM-3 A(kc=0): issue now, covered by jet-2 math.
    #pragma unroll
    for (int rt = 0; rt < 4; ++rt) a0[rt] = wsA3[(4 * w + rt) * 512 + lane];

    // ---------------- jet 2 (lane-local) -> new B fragments ----------------
    // Wave w's 64 rows are k-tiles 2w,2w+1; permuted k-order
    // k(qc,j)=16(j>>2)+4qc+(j&3): slot j=(rt&1)*4+r, tile kt2=rt>>1.
    // L-stream: L_h = s*L_u + c*(cxx*ux^2 + cyy*uy^2 + czz*uz^2).
    #pragma unroll
    for (int rt = 0; rt < 4; ++rt) {
        const float4 bb = *(const float4*)(b2 + w * 64 + rt * 16 + qc * 4);
        const float bbv[4] = {bb.x, bb.y, bb.z, bb.w};
        #pragma unroll
        for (int r = 0; r < 4; ++r) {
            float t = fast_tanh(acc[rt][0][r] + bbv[r]);
            float s = 1.f - t * t, c = -2.f * t * s;
            float ux = acc[rt][1][r], uy = acc[rt][2][r], uz = acc[rt][3][r];
            float wq = fmaf(CXX * ux, ux, fmaf(CYY * uy, uy, CZZ * uz * uz));
            acc[rt][0][r] = t;
            acc[rt][1][r] = s * ux; acc[rt][2][r] = s * uy; acc[rt][3][r] = s * uz;
            acc[rt][4][r] = fmaf(s, acc[rt][4][r], c * wq);
        }
    }
    #pragma unroll
    for (int s = 0; s < NS; ++s)
        #pragma unroll
        for (int kt2 = 0; kt2 < 2; ++kt2) {
            union { short8 s8; uint_t u4[4]; } v;
            v.u4[0] = pack2bf(acc[2 * kt2][s][0], acc[2 * kt2][s][1]);
            v.u4[1] = pack2bf(acc[2 * kt2][s][2], acc[2 * kt2][s][3]);
            v.u4[2] = pack2bf(acc[2 * kt2 + 1][s][0], acc[2 * kt2 + 1][s][1]);
            v.u4[3] = pack2bf(acc[2 * kt2 + 1][s][2], acc[2 * kt2 + 1][s][3]);
            Bsh[(s * 8 + 2 * w + kt2) * 64 + lane] = v.s8;   // own lane slot
        }
    __syncthreads();

    // ---------------- GEMM 3 ----------------
    run_gemm(wsA3);

    // ---------------- jet 3 + layer-4 partials (lane-local) ----------------
    // Layer-4 is linear: needs only value and L streams.
    float pt[4] = {0.f, 0.f, 0.f, 0.f};
    #pragma unroll
    for (int rt = 0; rt < 4; ++rt) {
        const int rb = w * 64 + rt * 16 + qc * 4;
        const float4 bb = *(const float4*)(b3 + rb);
        const float4 w0 = *(const float4*)(W4 + rb);
        const float4 w1 = *(const float4*)(W4 + 256 + rb);
        const float bbv[4] = {bb.x, bb.y, bb.z, bb.w};
        const float w0v[4] = {w0.x, w0.y, w0.z, w0.w};
        const float w1v[4] = {w1.x, w1.y, w1.z, w1.w};
        #pragma unroll
        for (int r = 0; r < 4; ++r) {
            float t = fast_tanh(acc[rt][0][r] + bbv[r]);
            float s = 1.f - t * t, c = -2.f * t * s;
            float ux = acc[rt][1][r], uy = acc[rt][2][r], uz = acc[rt][3][r];
            float wq = fmaf(CXX * ux, ux, fmaf(CYY * uy, uy, CZZ * uz * uz));
            float hL = fmaf(s, acc[rt][4][r], c * wq);
            pt[0] = fmaf(w0v[r], t, pt[0]);
            pt[1] = fmaf(w0v[r], hL, pt[1]);
            pt[2] = fmaf(w1v[r], t, pt[2]);
            pt[3] = fmaf(w1v[r], hL, pt[3]);
        }
    }
    #pragma unroll
    for (int k = 0; k < 4; ++k) {
        pt[k] += __shfl_xor(pt[k], 16, 64);
        pt[k] += __shfl_xor(pt[k], 32, 64);
    }
    if (qc == 0)
        *(float4*)&red[w][n15][0] = make_float4(pt[0], pt[1], pt[2], pt[3]);
    __syncthreads();

    if (tid < 16 && (pbase + tid) < N) {
        const int n = pbase + tid;
        float s4[4] = {0.f, 0.f, 0.f, 0.f};
        #pragma unroll
        for (int ww = 0; ww < 4; ++ww)
            #pragma unroll
            for (int k = 0; k < 4; ++k) s4[k] += red[ww][tid][k];
        const float fi = gf[n];
        const float PI = 3.14159265358979323846f;
        const float kw = 2.f * PI * (fi * 500.f + 100.f) / 343.f;
        const float vol = 0.7f * 0.5f * 0.6f;
        const float kk = vol * vol * kw * kw;
        const float pr = s4[0] + b4[0];
        const float pim = s4[2] + b4[1];
        out[n]     = 2.0f * s4[1] + kk * (pr * 2.0f + 0.1f);
        out[N + n] = 1.5f * s4[3] + kk * (pim * 1.5f - 0.05f);
    }
}

extern "C" void kernel_launch(void* const* d_in, const int* in_sizes, int n_in,
                              void* d_out, int out_size, void* d_ws, size_t ws_size,
                              hipStream_t stream) {
    const float* x = (const float*)d_in[0];
    const float* y = (const float*)d_in[1];
    const float* z = (const float*)d_in[2];
    const float* f = (const float*)d_in[3];
    const float* W1 = (const float*)d_in[4];
    const float* b1 = (const float*)d_in[5];
    const float* W2 = (const float*)d_in[6];
    const float* b2 = (const float*)d_in[7];
    const float* W3 = (const float*)d_in[8];
    const float* b3 = (const float*)d_in[9];
    const float* W4 = (const float*)d_in[10];
    const float* b4 = (const float*)d_in[11];
    float* out = (float*)d_out;
    const int N = in_sizes[0];
    const int grid = (N + PBLK - 1) / PBLK;

    prep_split<<<64, 256, 0, stream>>>(W2, W3, (short8*)d_ws);
    bvp_main<<<grid, 256, 0, stream>>>(x, y, z, f, W1, b1, b2, b3, W4, b4,
                                       (const short8*)d_ws, out, N);
}

// Round 10
// 258.246 us; speedup vs baseline: 1.0818x; 1.0818x over previous
//
#include <hip/hip_runtime.h>
#include <math.h>

// BVP Helmholtz-residual PINN via MFMA, round 16.
// Round-15 stagger FAILED (201->232, MFMA-pipe time constant at ~78us):
// de-phased blocks gained nothing -> phase-exclusivity (convoy) is NOT the
// binding constraint. Surviving hypothesis: per-wave MFMA issue density
// (~18%/wave, r8 datum) x thin TLP (3 waves/SIMD). Lever never pulled:
// MORE waves/SIMD. Occupancy was LDS-capped at 3 blocks/CU only by the
// 1KB red[] scratch: Bsh = 40960B and 4x40960 = 163840 = exactly 160KiB.
// Round-16: (1) alias red onto Bsh (dead after GEMM-3; one extra barrier
// between GEMM-3 reads and red stores) -> 4 blocks/CU, 4 waves/SIMD,
// launch_bounds(256,4) caps 128 VGPR (we use ~84).
// (2) fast_tanh: replace precise-div 2/(e+1) (~10 VALU) with
// (e-1)*v_rcp(e+1) (~4 VALU + trans); |u| structurally <= ~13 -> no inf.

typedef __attribute__((ext_vector_type(8))) short short8;
typedef __attribute__((ext_vector_type(4))) float floatx4;
typedef unsigned short ushort_t;
typedef unsigned int uint_t;

#define PBLK 16
#define NS 5   // jet streams: 0=v 1=dx 2=dy 3=dz 4=weighted-Laplacian

#define CXX 0.09f     // (YC*ZC)^2 = (0.5*0.6)^2
#define CYY 0.1764f   // (XC*ZC)^2 = (0.7*0.6)^2
#define CZZ 0.1225f   // (XC*YC)^2 = (0.7*0.5)^2

__device__ __forceinline__ ushort_t f2bf(float f) {
    uint_t u = __float_as_uint(f);
    return (ushort_t)((u + 0x7FFFu + ((u >> 16) & 1u)) >> 16);  // RNE
}
// pack2bf(f0,f1): {bf16(f0), bf16(f1)} in one u32 (f0 low). Round-half-up.
__device__ __forceinline__ uint_t pack2bf(float f0, float f1) {
    uint_t u0 = __float_as_uint(f0) + 0x8000u;
    uint_t u1 = __float_as_uint(f1) + 0x8000u;
    return __builtin_amdgcn_perm(u1, u0, 0x07060302u);
}
// tanh = (e-1)/(e+1), e = exp(2u); native rcp (no precise-div sequence).
// |u| bounded ~13 by network structure -> e finite, no inf*0 path.
__device__ __forceinline__ float fast_tanh(float u) {
    float e = __expf(2.f * u);
    return (e - 1.f) * __builtin_amdgcn_rcpf(e + 1.f);
}

// ws: 2 layers x 16 row-tiles x 8 kc x 64 lanes x 16B = 256 KB.
// A-frag lane (m=lane&15, qa=lane>>4) slot j:
//   layer0 (W2, natural):  col = kc*32 + 8*qa + j
//   layer1 (W3, permuted): col = kc*32 + 16*(j>>2) + 4*qa + (j&3)
__global__ void prep_split(const float* __restrict__ W2, const float* __restrict__ W3,
                           short8* __restrict__ ws) {
    int t16 = blockIdx.x * blockDim.x + threadIdx.x;  // 0..16383
    int lane = t16 & 63;
    int kc = (t16 >> 6) & 7;
    int tt = (t16 >> 9) & 15;
    int l = t16 >> 13;
    const float* W = l ? W3 : W2;
    int row = tt * 16 + (lane & 15);
    int qa = lane >> 4;
    const float* src = W + row * 256 + kc * 32 + (l ? 4 * qa : 8 * qa);
    float4 va = *(const float4*)src;
    float4 vb = *(const float4*)(src + (l ? 16 : 4));
    float v[8] = {va.x, va.y, va.z, va.w, vb.x, vb.y, vb.z, vb.w};
    short8 hi8;
    #pragma unroll
    for (int j = 0; j < 8; ++j) hi8[j] = (short)f2bf(v[j]);   // RNE (runs once)
    ws[l * 8192 + tt * 512 + kc * 64 + lane] = hi8;
}

__global__ __launch_bounds__(256, 4)
void bvp_main(const float* __restrict__ gx, const float* __restrict__ gy,
              const float* __restrict__ gz, const float* __restrict__ gf,
              const float* __restrict__ W1, const float* __restrict__ b1,
              const float* __restrict__ b2, const float* __restrict__ b3,
              const float* __restrict__ W4, const float* __restrict__ b4,
              const short8* __restrict__ wsA, float* __restrict__ out, int N) {
    // 40960 B: B[s][kt][lane]. red[] aliases the head of Bsh (Bsh is dead
    // after GEMM-3; a barrier separates last Bsh read from red stores).
    __shared__ short8 Bsh[NS * 8 * 64];
    float (*red)[16][4] = (float (*)[16][4])Bsh;   // [4][16][4] = 1 KB

    const int tid = threadIdx.x;
    const int w = tid >> 6, lane = tid & 63;   // w in 0..3
    const int n15 = lane & 15, qc = lane >> 4;
    const int pbase = blockIdx.x * PBLK;
    const short8* __restrict__ wsA3 = wsA + 8192;

    floatx4 acc[4][NS];  // 4 row-tiles (64 rows) x 5 streams = 80 VGPR
    short8 a0[4], a1[4];

    // GEMM-2 A(kc=0): issue now, covered by layer-1 math.
    #pragma unroll
    for (int rt = 0; rt < 4; ++rt) a0[rt] = wsA[(4 * w + rt) * 512 + lane];

    // ---------------- layer 1 (VALU) -> B fragments ----------------
    // pp = tid&15: 16-lane groups write contiguous 256B -> conflict-free;
    // 256 threads: each handles two u8 neuron-groups sequentially.
    // u linear in x,y,z -> L_u = 0, so L_h = c*(cxx*wx^2+cyy*wy^2+czz*wz^2).
    {
        const int pp = tid & 15;
        const int pidx = min(pbase + pp, N - 1);
        const float xi = gx[pidx], yi = gy[pidx], zi = gz[pidx], fi = gf[pidx];
        #pragma unroll
        for (int g = 0; g < 2; ++g) {
            const int u8 = (tid >> 4) + 16 * g;   // 0..31: neurons 8*u8..+7
            float hv[NS][8];
            #pragma unroll
            for (int r = 0; r < 8; ++r) {
                const int i = u8 * 8 + r;
                float4 wv = *(const float4*)(W1 + 4 * i);
                float u = fmaf(wv.x, xi, fmaf(wv.y, yi, fmaf(wv.z, zi, fmaf(wv.w, fi, b1[i]))));
                float t = fast_tanh(u), s = 1.f - t * t, c = -2.f * t * s;
                float wq = fmaf(CXX * wv.x, wv.x, fmaf(CYY * wv.y, wv.y, CZZ * wv.z * wv.z));
                hv[0][r] = t;
                hv[1][r] = s * wv.x; hv[2][r] = s * wv.y; hv[3][r] = s * wv.z;
                hv[4][r] = c * wq;
            }
            const int kt = u8 >> 2, qb = u8 & 3;  // k-slot qb*8+r (natural order)
            #pragma unroll
            for (int s = 0; s < NS; ++s) {
                union { short8 s8; uint_t u4[4]; } v;
                #pragma unroll
                for (int j = 0; j < 4; ++j)
                    v.u4[j] = pack2bf(hv[s][2 * j], hv[s][2 * j + 1]);
                Bsh[(s * 8 + kt) * 64 + qb * 16 + pp] = v.s8;
            }
        }
    }
    __syncthreads();

    // K-loop: A 1-deep global prefetch (L2-resident), B single-buffer LDS.
    // One ds_read_b128 feeds 4 MFMAs (rt reuse x4).
    auto run_gemm = [&](const short8* __restrict__ A) {
        #pragma unroll
        for (int rt = 0; rt < 4; ++rt)
            #pragma unroll
            for (int ct = 0; ct < NS; ++ct) acc[rt][ct] = (floatx4){0.f, 0.f, 0.f, 0.f};
        #pragma unroll
        for (int kc = 0; kc < 8; ++kc) {
            if (kc < 7) {
                #pragma unroll
                for (int rt = 0; rt < 4; ++rt)
                    a1[rt] = A[(4 * w + rt) * 512 + (kc + 1) * 64 + lane];
            }
            short8 b[NS];
            #pragma unroll
            for (int ct = 0; ct < NS; ++ct) b[ct] = Bsh[(ct * 8 + kc) * 64 + lane];
            #pragma unroll
            for (int ct = 0; ct < NS; ++ct)
                #pragma unroll
                for (int rt = 0; rt < 4; ++rt)
                    acc[rt][ct] = __builtin_amdgcn_mfma_f32_16x16x32_bf16(a0[rt], b[ct], acc[rt][ct], 0, 0, 0);
            if (kc < 7) {
                #pragma unroll
                for (int rt = 0; rt < 4; ++rt) a0[rt] = a1[rt];
            }
        }
    };

    // ---------------- GEMM 2 ----------------
    run_gemm(wsA);
    __syncthreads();   // all waves done reading layer-2 B

    // GEMM-3 A(kc=0): issue now, covered by jet-2 math.
    #pragma unroll
    for (int rt = 0; rt < 4; ++rt) a0[rt] = wsA3[(4 * w + rt) * 512 + lane];

    // ---------------- jet 2 (lane-local) -> new B fragments ----------------
    // Wave w's 64 rows are k-tiles 2w,2w+1; permuted k-order
    // k(qc,j)=16(j>>2)+4qc+(j&3): slot j=(rt&1)*4+r, tile kt2=rt>>1.
    // L-stream: L_h = s*L_u + c*(cxx*ux^2 + cyy*uy^2 + czz*uz^2).
    #pragma unroll
    for (int rt = 0; rt < 4; ++rt) {
        const float4 bb = *(const float4*)(b2 + w * 64 + rt * 16 + qc * 4);
        const float bbv[4] = {bb.x, bb.y, bb.z, bb.w};
        #pragma unroll
        for (int r = 0; r < 4; ++r) {
            float t = fast_tanh(acc[rt][0][r] + bbv[r]);
            float s = 1.f - t * t, c = -2.f * t * s;
            float ux = acc[rt][1][r], uy = acc[rt][2][r], uz = acc[rt][3][r];
            float wq = fmaf(CXX * ux, ux, fmaf(CYY * uy, uy, CZZ * uz * uz));
            acc[rt][0][r] = t;
            acc[rt][1][r] = s * ux; acc[rt][2][r] = s * uy; acc[rt][3][r] = s * uz;
            acc[rt][4][r] = fmaf(s, acc[rt][4][r], c * wq);
        }
    }
    #pragma unroll
    for (int s = 0; s < NS; ++s)
        #pragma unroll
        for (int kt2 = 0; kt2 < 2; ++kt2) {
            union { short8 s8; uint_t u4[4]; } v;
            v.u4[0] = pack2bf(acc[2 * kt2][s][0], acc[2 * kt2][s][1]);
            v.u4[1] = pack2bf(acc[2 * kt2][s][2], acc[2 * kt2][s][3]);
            v.u4[2] = pack2bf(acc[2 * kt2 + 1][s][0], acc[2 * kt2 + 1][s][1]);
            v.u4[3] = pack2bf(acc[2 * kt2 + 1][s][2], acc[2 * kt2 + 1][s][3]);
            Bsh[(s * 8 + 2 * w + kt2) * 64 + lane] = v.s8;   // own lane slot
        }
    __syncthreads();

    // ---------------- GEMM 3 ----------------
    run_gemm(wsA3);

    // ---------------- jet 3 + layer-4 partials (lane-local) ----------------
    // Layer-4 is linear: needs only value and L streams.
    float pt[4] = {0.f, 0.f, 0.f, 0.f};
    #pragma unroll
    for (int rt = 0; rt < 4; ++rt) {
        const int rb = w * 64 + rt * 16 + qc * 4;
        const float4 bb = *(const float4*)(b3 + rb);
        const float4 w0 = *(const float4*)(W4 + rb);
        const float4 w1 = *(const float4*)(W4 + 256 + rb);
        const float bbv[4] = {bb.x, bb.y, bb.z, bb.w};
        const float w0v[4] = {w0.x, w0.y, w0.z, w0.w};
        const float w1v[4] = {w1.x, w1.y, w1.z, w1.w};
        #pragma unroll
        for (int r = 0; r < 4; ++r) {
            float t = fast_tanh(acc[rt][0][r] + bbv[r]);
            float s = 1.f - t * t, c = -2.f * t * s;
            float ux = acc[rt][1][r], uy = acc[rt][2][r], uz = acc[rt][3][r];
            float wq = fmaf(CXX * ux, ux, fmaf(CYY * uy, uy, CZZ * uz * uz));
            float hL = fmaf(s, acc[rt][4][r], c * wq);
            pt[0] = fmaf(w0v[r], t, pt[0]);
            pt[1] = fmaf(w0v[r], hL, pt[1]);
            pt[2] = fmaf(w1v[r], t, pt[2]);
            pt[3] = fmaf(w1v[r], hL, pt[3]);
        }
    }
    #pragma unroll
    for (int k = 0; k < 4; ++k) {
        pt[k] += __shfl_xor(pt[k], 16, 64);
        pt[k] += __shfl_xor(pt[k], 32, 64);
    }
    // Bsh is dead from here; drain ALL waves' GEMM-3 reads before the
    // aliased red[] stores.
    __syncthreads();
    if (qc == 0)
        *(float4*)&red[w][n15][0] = make_float4(pt[0], pt[1], pt[2], pt[3]);
    __syncthreads();

    if (tid < 16 && (pbase + tid) < N) {
        const int n = pbase + tid;
        float s4[4] = {0.f, 0.f, 0.f, 0.f};
        #pragma unroll
        for (int ww = 0; ww < 4; ++ww)
            #pragma unroll
            for (int k = 0; k < 4; ++k) s4[k] += red[ww][tid][k];
        const float fi = gf[n];
        const float PI = 3.14159265358979323846f;
        const float kw = 2.f * PI * (fi * 500.f + 100.f) / 343.f;
        const float vol = 0.7f * 0.5f * 0.6f;
        const float kk = vol * vol * kw * kw;
        const float pr = s4[0] + b4[0];
        const float pim = s4[2] + b4[1];
        out[n]     = 2.0f * s4[1] + kk * (pr * 2.0f + 0.1f);
        out[N + n] = 1.5f * s4[3] + kk * (pim * 1.5f - 0.05f);
    }
}

extern "C" void kernel_launch(void* const* d_in, const int* in_sizes, int n_in,
                              void* d_out, int out_size, void* d_ws, size_t ws_size,
                              hipStream_t stream) {
    const float* x = (const float*)d_in[0];
    const float* y = (const float*)d_in[1];
    const float* z = (const float*)d_in[2];
    const float* f = (const float*)d_in[3];
    const float* W1 = (const float*)d_in[4];
    const float* b1 = (const float*)d_in[5];
    const float* W2 = (const float*)d_in[6];
    const float* b2 = (const float*)d_in[7];
    const float* W3 = (const float*)d_in[8];
    const float* b3 = (const float*)d_in[9];
    const float* W4 = (const float*)d_in[10];
    const float* b4 = (const float*)d_in[11];
    float* out = (float*)d_out;
    const int N = in_sizes[0];
    const int grid = (N + PBLK - 1) / PBLK;

    prep_split<<<64, 256, 0, stream>>>(W2, W3, (short8*)d_ws);
    bvp_main<<<grid, 256, 0, stream>>>(x, y, z, f, W1, b1, b2, b3, W4, b4,
                                       (const short8*)d_ws, out, N);
}

// Round 11
// 256.711 us; speedup vs baseline: 1.0883x; 1.0060x over previous
//
#include <hip/hip_runtime.h>
#include <math.h>

// BVP Helmholtz-residual PINN via MFMA, round 17.
// Round-16 post-mortem: 4 blocks/CU worked (Occ 30->40%, 201->196.5us)
// BUT the 128-VGPR cap spilled the GEMM live set (acc80+a0/a1 32+b20+addr
// ~148): WRITE_SIZE 1MB->155MB scratch, VGPR_Count 64, MfmaUtil only 41.
// Round-17: keep 4 blocks/CU, remove the spill by SHRINKING the live set
// instead of capping the allocator: drop explicit A double-buffer (-16)
// and the b[5] array (-16); load A per-kc, B per-ct directly. Live ~110
// of 128 -> ~18 spare regs for the compiler's own hoisting (r9: its
// scheduling is adequate). Latency covered by 4-waves/SIMD TLP (what the
// occupancy was bought for). Everything else = round-16 verbatim.

typedef __attribute__((ext_vector_type(8))) short short8;
typedef __attribute__((ext_vector_type(4))) float floatx4;
typedef unsigned short ushort_t;
typedef unsigned int uint_t;

#define PBLK 16
#define NS 5   // jet streams: 0=v 1=dx 2=dy 3=dz 4=weighted-Laplacian

#define CXX 0.09f     // (YC*ZC)^2 = (0.5*0.6)^2
#define CYY 0.1764f   // (XC*ZC)^2 = (0.7*0.6)^2
#define CZZ 0.1225f   // (XC*YC)^2 = (0.7*0.5)^2

__device__ __forceinline__ ushort_t f2bf(float f) {
    uint_t u = __float_as_uint(f);
    return (ushort_t)((u + 0x7FFFu + ((u >> 16) & 1u)) >> 16);  // RNE
}
// pack2bf(f0,f1): {bf16(f0), bf16(f1)} in one u32 (f0 low). Round-half-up.
__device__ __forceinline__ uint_t pack2bf(float f0, float f1) {
    uint_t u0 = __float_as_uint(f0) + 0x8000u;
    uint_t u1 = __float_as_uint(f1) + 0x8000u;
    return __builtin_amdgcn_perm(u1, u0, 0x07060302u);
}
// tanh = (e-1)/(e+1), e = exp(2u); native rcp (no precise-div sequence).
// |u| bounded ~13 by network structure -> e finite, no inf*0 path.
__device__ __forceinline__ float fast_tanh(float u) {
    float e = __expf(2.f * u);
    return (e - 1.f) * __builtin_amdgcn_rcpf(e + 1.f);
}

// ws: 2 layers x 16 row-tiles x 8 kc x 64 lanes x 16B = 256 KB.
// A-frag lane (m=lane&15, qa=lane>>4) slot j:
//   layer0 (W2, natural):  col = kc*32 + 8*qa + j
//   layer1 (W3, permuted): col = kc*32 + 16*(j>>2) + 4*qa + (j&3)
__global__ void prep_split(const float* __restrict__ W2, const float* __restrict__ W3,
                           short8* __restrict__ ws) {
    int t16 = blockIdx.x * blockDim.x + threadIdx.x;  // 0..16383
    int lane = t16 & 63;
    int kc = (t16 >> 6) & 7;
    int tt = (t16 >> 9) & 15;
    int l = t16 >> 13;
    const float* W = l ? W3 : W2;
    int row = tt * 16 + (lane & 15);
    int qa = lane >> 4;
    const float* src = W + row * 256 + kc * 32 + (l ? 4 * qa : 8 * qa);
    float4 va = *(const float4*)src;
    float4 vb = *(const float4*)(src + (l ? 16 : 4));
    float v[8] = {va.x, va.y, va.z, va.w, vb.x, vb.y, vb.z, vb.w};
    short8 hi8;
    #pragma unroll
    for (int j = 0; j < 8; ++j) hi8[j] = (short)f2bf(v[j]);   // RNE (runs once)
    ws[l * 8192 + tt * 512 + kc * 64 + lane] = hi8;
}

__global__ __launch_bounds__(256, 4)
void bvp_main(const float* __restrict__ gx, const float* __restrict__ gy,
              const float* __restrict__ gz, const float* __restrict__ gf,
              const float* __restrict__ W1, const float* __restrict__ b1,
              const float* __restrict__ b2, const float* __restrict__ b3,
              const float* __restrict__ W4, const float* __restrict__ b4,
              const short8* __restrict__ wsA, float* __restrict__ out, int N) {
    // 40960 B: B[s][kt][lane]. red[] aliases the head of Bsh (Bsh is dead
    // after GEMM-3; a barrier separates last Bsh read from red stores).
    __shared__ short8 Bsh[NS * 8 * 64];
    float (*red)[16][4] = (float (*)[16][4])Bsh;   // [4][16][4] = 1 KB

    const int tid = threadIdx.x;
    const int w = tid >> 6, lane = tid & 63;   // w in 0..3
    const int n15 = lane & 15, qc = lane >> 4;
    const int pbase = blockIdx.x * PBLK;
    const short8* __restrict__ wsA3 = wsA + 8192;

    floatx4 acc[4][NS];  // 4 row-tiles (64 rows) x 5 streams = 80 VGPR

    // ---------------- layer 1 (VALU) -> B fragments ----------------
    // pp = tid&15: 16-lane groups write contiguous 256B -> conflict-free;
    // 256 threads: each handles two u8 neuron-groups sequentially.
    // u linear in x,y,z -> L_u = 0, so L_h = c*(cxx*wx^2+cyy*wy^2+czz*wz^2).
    {
        const int pp = tid & 15;
        const int pidx = min(pbase + pp, N - 1);
        const float xi = gx[pidx], yi = gy[pidx], zi = gz[pidx], fi = gf[pidx];
        #pragma unroll
        for (int g = 0; g < 2; ++g) {
            const int u8 = (tid >> 4) + 16 * g;   // 0..31: neurons 8*u8..+7
            float hv[NS][8];
            #pragma unroll
            for (int r = 0; r < 8; ++r) {
                const int i = u8 * 8 + r;
                float4 wv = *(const float4*)(W1 + 4 * i);
                float u = fmaf(wv.x, xi, fmaf(wv.y, yi, fmaf(wv.z, zi, fmaf(wv.w, fi, b1[i]))));
                float t = fast_tanh(u), s = 1.f - t * t, c = -2.f * t * s;
                float wq = fmaf(CXX * wv.x, wv.x, fmaf(CYY * wv.y, wv.y, CZZ * wv.z * wv.z));
                hv[0][r] = t;
                hv[1][r] = s * wv.x; hv[2][r] = s * wv.y; hv[3][r] = s * wv.z;
                hv[4][r] = c * wq;
            }
            const int kt = u8 >> 2, qb = u8 & 3;  // k-slot qb*8+r (natural order)
            #pragma unroll
            for (int s = 0; s < NS; ++s) {
                union { short8 s8; uint_t u4[4]; } v;
                #pragma unroll
                for (int j = 0; j < 4; ++j)
                    v.u4[j] = pack2bf(hv[s][2 * j], hv[s][2 * j + 1]);
                Bsh[(s * 8 + kt) * 64 + qb * 16 + pp] = v.s8;
            }
        }
    }
    __syncthreads();

    // K-loop: direct A (L2-resident) and B (LDS) loads; live set ~110 regs
    // leaves the 128-cap allocator ~18 spare for its own hoisting.
    // One ds_read_b128 feeds 4 MFMAs (rt reuse x4).
    auto run_gemm = [&](const short8* __restrict__ A) {
        #pragma unroll
        for (int rt = 0; rt < 4; ++rt)
            #pragma unroll
            for (int ct = 0; ct < NS; ++ct) acc[rt][ct] = (floatx4){0.f, 0.f, 0.f, 0.f};
        #pragma unroll
        for (int kc = 0; kc < 8; ++kc) {
            short8 av[4];
            #pragma unroll
            for (int rt = 0; rt < 4; ++rt)
                av[rt] = A[(4 * w + rt) * 512 + kc * 64 + lane];
            #pragma unroll
            for (int ct = 0; ct < NS; ++ct) {
                const short8 b = Bsh[(ct * 8 + kc) * 64 + lane];
                #pragma unroll
                for (int rt = 0; rt < 4; ++rt)
                    acc[rt][ct] = __builtin_amdgcn_mfma_f32_16x16x32_bf16(av[rt], b, acc[rt][ct], 0, 0, 0);
            }
        }
    };

    // ---------------- GEMM 2 ----------------
    run_gemm(wsA);
    __syncthreads();   // all waves done reading layer-2 B

    // ---------------- jet 2 (lane-local) -> new B fragments ----------------
    // Wave w's 64 rows are k-tiles 2w,2w+1; permuted k-order
    // k(qc,j)=16(j>>2)+4qc+(j&3): slot j=(rt&1)*4+r, tile kt2=rt>>1.
    // L-stream: L_h = s*L_u + c*(cxx*ux^2 + cyy*uy^2 + czz*uz^2).
    #pragma unroll
    for (int rt = 0; rt < 4; ++rt) {
        const float4 bb = *(const float4*)(b2 + w * 64 + rt * 16 + qc * 4);
        const float bbv[4] = {bb.x, bb.y, bb.z, bb.w};
        #pragma unroll
        for (int r = 0; r < 4; ++r) {
            float t = fast_tanh(acc[rt][0][r] + bbv[r]);
            float s = 1.f - t * t, c = -2.f * t * s;
            float ux = acc[rt][1][r], uy = acc[rt][2][r], uz = acc[rt][3][r];
            float wq = fmaf(CXX * ux, ux, fmaf(CYY * uy, uy, CZZ * uz * uz));
            acc[rt][0][r] = t;
            acc[rt][1][r] = s * ux; acc[rt][2][r] = s * uy; acc[rt][3][r] = s * uz;
            acc[rt][4][r] = fmaf(s, acc[rt][4][r], c * wq);
        }
    }
    #pragma unroll
    for (int s = 0; s < NS; ++s)
        #pragma unroll
        for (int kt2 = 0; kt2 < 2; ++kt2) {
            union { short8 s8; uint_t u4[4]; } v;
            v.u4[0] = pack2bf(acc[2 * kt2][s][0], acc[2 * kt2][s][1]);
            v.u4[1] = pack2bf(acc[2 * kt2][s][2], acc[2 * kt2][s][3]);
            v.u4[2] = pack2bf(acc[2 * kt2 + 1][s][0], acc[2 * kt2 + 1][s][1]);
            v.u4[3] = pack2bf(acc[2 * kt2 + 1][s][2], acc[2 * kt2 + 1][s][3]);
            Bsh[(s * 8 + 2 * w + kt2) * 64 + lane] = v.s8;   // own lane slot
        }
    __syncthreads();

    // ---------------- GEMM 3 ----------------
    run_gemm(wsA3);

    // ---------------- jet 3 + layer-4 partials (lane-local) ----------------
    // Layer-4 is linear: needs only value and L streams.
    float pt[4] = {0.f, 0.f, 0.f, 0.f};
    #pragma unroll
    for (int rt = 0; rt < 4; ++rt) {
        const int rb = w * 64 + rt * 16 + qc * 4;
        const float4 bb = *(const float4*)(b3 + rb);
        const float4 w0 = *(const float4*)(W4 + rb);
        const float4 w1 = *(const float4*)(W4 + 256 + rb);
        const float bbv[4] = {bb.x, bb.y, bb.z, bb.w};
        const float w0v[4] = {w0.x, w0.y, w0.z, w0.w};
        const float w1v[4] = {w1.x, w1.y, w1.z, w1.w};
        #pragma unroll
        for (int r = 0; r < 4; ++r) {
            float t = fast_tanh(acc[rt][0][r] + bbv[r]);
            float s = 1.f - t * t, c = -2.f * t * s;
            float ux = acc[rt][1][r], uy = acc[rt][2][r], uz = acc[rt][3][r];
            float wq = fmaf(CXX * ux, ux, fmaf(CYY * uy, uy, CZZ * uz * uz));
            float hL = fmaf(s, acc[rt][4][r], c * wq);
            pt[0] = fmaf(w0v[r], t, pt[0]);
            pt[1] = fmaf(w0v[r], hL, pt[1]);
            pt[2] = fmaf(w1v[r], t, pt[2]);
            pt[3] = fmaf(w1v[r], hL, pt[3]);
        }
    }
    #pragma unroll
    for (int k = 0; k < 4; ++k) {
        pt[k] += __shfl_xor(pt[k], 16, 64);
        pt[k] += __shfl_xor(pt[k], 32, 64);
    }
    // Bsh is dead from here; drain ALL waves' GEMM-3 reads before the
    // aliased red[] stores.
    __syncthreads();
    if (qc == 0)
        *(float4*)&red[w][n15][0] = make_float4(pt[0], pt[1], pt[2], pt[3]);
    __syncthreads();

    if (tid < 16 && (pbase + tid) < N) {
        const int n = pbase + tid;
        float s4[4] = {0.f, 0.f, 0.f, 0.f};
        #pragma unroll
        for (int ww = 0; ww < 4; ++ww)
            #pragma unroll
            for (int k = 0; k < 4; ++k) s4[k] += red[ww][tid][k];
        const float fi = gf[n];
        const float PI = 3.14159265358979323846f;
        const float kw = 2.f * PI * (fi * 500.f + 100.f) / 343.f;
        const float vol = 0.7f * 0.5f * 0.6f;
        const float kk = vol * vol * kw * kw;
        const float pr = s4[0] + b4[0];
        const float pim = s4[2] + b4[1];
        out[n]     = 2.0f * s4[1] + kk * (pr * 2.0f + 0.1f);
        out[N + n] = 1.5f * s4[3] + kk * (pim * 1.5f - 0.05f);
    }
}

extern "C" void kernel_launch(void* const* d_in, const int* in_sizes, int n_in,
                              void* d_out, int out_size, void* d_ws, size_t ws_size,
                              hipStream_t stream) {
    const float* x = (const float*)d_in[0];
    const float* y = (const float*)d_in[1];
    const float* z = (const float*)d_in[2];
    const float* f = (const float*)d_in[3];
    const float* W1 = (const float*)d_in[4];
    const float* b1 = (const float*)d_in[5];
    const float* W2 = (const float*)d_in[6];
    const float* b2 = (const float*)d_in[7];
    const float* W3 = (const float*)d_in[8];
    const float* b3 = (const float*)d_in[9];
    const float* W4 = (const float*)d_in[10];
    const float* b4 = (const float*)d_in[11];
    float* out = (float*)d_out;
    const int N = in_sizes[0];
    const int grid = (N + PBLK - 1) / PBLK;

    prep_split<<<64, 256, 0, stream>>>(W2, W3, (short8*)d_ws);
    bvp_main<<<grid, 256, 0, stream>>>(x, y, z, f, W1, b1, b2, b3, W4, b4,
                                       (const short8*)d_ws, out, N);
}